// Round 11
// baseline (445.913 us; speedup 1.0000x reference)
//
#include <hip/hip_runtime.h>
#include <math.h>

#define Bq 64
#define Tq 1024
#define Nq 128

typedef __attribute__((ext_vector_type(2))) _Float16 h2;

#if defined(__has_builtin)
#  if __has_builtin(__builtin_amdgcn_fdot2)
#    define HAVE_FDOT2 1
#  endif
#  if __has_builtin(__builtin_amdgcn_rcpf)
#    define HAVE_RCPF 1
#  endif
#endif

__device__ __forceinline__ float dot2acc(h2 a, h2 b, float c) {
#ifdef HAVE_FDOT2
    return __builtin_amdgcn_fdot2(a, b, c, false);
#else
    return c + (float)a.x * (float)b.x + (float)a.y * (float)b.y;
#endif
}

__device__ __forceinline__ float fastrcp(float x) {
#ifdef HAVE_RCPF
    return __builtin_amdgcn_rcpf(x);
#else
    return 1.0f / x;
#endif
}

// LDS-only barrier: drain LDS ops, sync waves, but leave global/scratch loads
// (vmcnt) in flight across the barrier — the compiler's counted vmcnt waits
// handle their consumption points. (§5 8-phase pattern.)
#define LDS_BARRIER() asm volatile("s_waitcnt lgkmcnt(0)\n\ts_barrier" ::: "memory")

union Q16 { int4 v; h2 p[4]; };

#define EXP_NEG7 9.118819655545162e-4f

// ---------------------------------------------------------------------------
// One forward step (transition into time t). rb holds p_{t-1}; writes p_t to wb.
// Transcendental-free critical path (R10, proven absmax 0.0):
//   p_t[n] = min( (sum_m p_{t-1}[m] E[m][n]) * ee_t[n] * rcp(pm)*e^-7, 60000 )
// pm = sampled max of p[0..3] (uniform across lanes via broadcast reads).
// Side chains (off critical path): Mcur += log(pm)+7; emission exp pipeline.
// ---------------------------------------------------------------------------
__device__ __forceinline__ void step_body(
    int t, int tsz, int n, const float* __restrict__ em_n,
    const _Float16* __restrict__ rb, _Float16* __restrict__ wb,
    const h2 (&e)[64],
    float& ee0, float& ee1, float& ee2, float& raw3, float& raw4,
    float& Mcur, float& plast)
{
    LDS_BARRIER();                         // p_{t-1} fully written in rb

    const int4* p4 = (const int4*)rb;
    Q16 U[16];
    #pragma unroll
    for (int q = 0; q < 16; ++q) U[q].v = p4[q];     // broadcast reads
    asm volatile("" ::: "memory");         // keep wb store below the reads

    // sampled max of p[0..3] (R3 recipe), identical in every lane
    float pm = fmaxf(fmaxf((float)U[0].p[0].x, (float)U[0].p[0].y),
                     fmaxf((float)U[0].p[1].x, (float)U[0].p[1].y));
    pm = fmaxf(pm, 1e-6f);
    const float f = ee0 * (fastrcp(pm) * EXP_NEG7);  // ready before dot2s end

    // issue emission load for step t+5 (off path; stays in flight across the
    // LDS-only barrier — no vmcnt drain anymore)
    const float raw5 = em_n[(size_t)min(t + 5, tsz - 1) * Nq];

    float s[4] = {0.f, 0.f, 0.f, 0.f};
    #pragma unroll
    for (int j = 0; j < 64; ++j)                     // static after unroll
        s[j & 3] = dot2acc(U[j >> 2].p[j & 3], e[j], s[j & 3]);
    const float ss = (s[0] + s[1]) + (s[2] + s[3]);

    const float pn = fminf(ss * f, 60000.0f);
    wb[n] = (_Float16)pn;
    plast = pn;

    // side chains (loop-carried only on themselves)
    Mcur += __logf(pm) + 7.0f;
    const float eeN = __expf(raw3);        // raw3 was loaded 3 steps ago
    ee0 = ee1; ee1 = ee2; ee2 = eeN;
    raw3 = raw4; raw4 = raw5;
}

// ---------------------------------------------------------------------------
// Blocks 0..63: forward chain b — 128 threads (2 waves), lane owns state n=tid.
//   E column n = 64 h2 VGPRs. One LDS-only barrier + one 256 B LDS round-trip
//   per step; global loads free-float across steps.
// Blocks 64..127: gold-path score for chain (blockIdx-64).
// ---------------------------------------------------------------------------
__global__ __launch_bounds__(128, 1)
void crf_kernel(const float* __restrict__ emissions,
                const int* __restrict__ token_sizes,
                const int* __restrict__ targets,
                const float* __restrict__ transitions,
                const float* __restrict__ head,
                const float* __restrict__ last,
                float* __restrict__ out) {
    const int tid = threadIdx.x;

    if (blockIdx.x >= Bq) {
        // ---------------- score path ----------------
        const int b = blockIdx.x - Bq;
        const int tsz = token_sizes[b];
        const int* tg = targets + b * Tq;
        const float* em = emissions + (size_t)b * Tq * Nq;
        float sc = 0.f;
        for (int t = tid; t < tsz; t += 128) {
            int cur = tg[t];
            sc += em[(size_t)t * Nq + cur];
            if (t >= 1) sc += transitions[tg[t - 1] * Nq + cur];
        }
        #pragma unroll
        for (int off = 32; off >= 1; off >>= 1)
            sc += __shfl_xor(sc, off, 64);
        __shared__ float wsum[2];
        if ((tid & 63) == 0) wsum[tid >> 6] = sc;
        __syncthreads();
        if (tid == 0)
            out[Bq + b] = wsum[0] + wsum[1] + head[tg[0]] + last[tg[tsz - 1]];
        return;
    }

    // ---------------- forward path ----------------
    const int n = tid;               // owned state
    const int wv = tid >> 6;
    const int l = tid & 63;
    const int b = blockIdx.x;
    const float* em_c = emissions + (size_t)b * Tq * Nq;
    const float* em_n = em_c + n;    // per-lane base: em_n[t*Nq] = emit_t[n]
    const int tsz = token_sizes[b];  // in [T/2, T]

    __shared__ __align__(16) _Float16 pbuf[2][Nq];
    __shared__ float redA[2], redB[2];

    // E column n: e[j] = (exp(T[2j][n]), exp(T[2j+1][n]))
    h2 e[64];
    #pragma unroll
    for (int j = 0; j < 64; ++j) {
        h2 v;
        v.x = (_Float16)__expf(transitions[(2 * j)     * Nq + n]);
        v.y = (_Float16)__expf(transitions[(2 * j + 1) * Nq + n]);
        e[j] = v;
    }
    #pragma unroll
    for (int j = 0; j < 64; ++j) asm volatile("" : "+v"(e[j]));

    // alpha0 and uniform M0 (one-time block reduce)
    const float a0 = head[n] + em_n[0];
    float Mcur;
    {
        float w = a0;
        #pragma unroll
        for (int off = 32; off >= 1; off >>= 1)
            w = fmaxf(w, __shfl_xor(w, off, 64));
        if (l == 0) redA[wv] = w;
        __syncthreads();
        Mcur = fmaxf(redA[0], redA[1]);
    }
    pbuf[0][n] = (_Float16)__expf(a0 - Mcur);   // p_0, in (0,1]

    // emission pipeline: ee for t=1,2,3 ; raw for t=4,5  (tsz >= 512)
    float ee0 = __expf(em_n[1 * Nq]);
    float ee1 = __expf(em_n[2 * Nq]);
    float ee2 = __expf(em_n[3 * Nq]);
    float raw3 = em_n[4 * Nq];
    float raw4 = em_n[5 * Nq];

    float plast = 0.f;
    _Float16* b0 = &pbuf[0][0];
    _Float16* b1 = &pbuf[1][0];

    // main loop: step t reads buf[(t-1)&1], writes buf[t&1]; start t=1
    int t = 1;
    for (; t + 3 <= tsz - 1; t += 4) {
        step_body(t,     tsz, n, em_n, b0, b1, e, ee0, ee1, ee2, raw3, raw4, Mcur, plast);
        step_body(t + 1, tsz, n, em_n, b1, b0, e, ee0, ee1, ee2, raw3, raw4, Mcur, plast);
        step_body(t + 2, tsz, n, em_n, b0, b1, e, ee0, ee1, ee2, raw3, raw4, Mcur, plast);
        step_body(t + 3, tsz, n, em_n, b1, b0, e, ee0, ee1, ee2, raw3, raw4, Mcur, plast);
    }
    // remainder (t ≡ 1 mod 4 here; tsz uniform per block -> uniform barriers)
    if (t <= tsz - 1) {
        step_body(t, tsz, n, em_n, b0, b1, e, ee0, ee1, ee2, raw3, raw4, Mcur, plast);
        ++t;
        if (t <= tsz - 1) {
            step_body(t, tsz, n, em_n, b1, b0, e, ee0, ee1, ee2, raw3, raw4, Mcur, plast);
            ++t;
            if (t <= tsz - 1)
                step_body(t, tsz, n, em_n, b0, b1, e, ee0, ee1, ee2, raw3, raw4, Mcur, plast);
        }
    }

    // ---- logZ = Mcur + log( sum_n p_final[n] * exp(last[n]) ) ----
    {
        float z = plast * __expf(last[n]);
        #pragma unroll
        for (int off = 32; off >= 1; off >>= 1)
            z += __shfl_xor(z, off, 64);
        if (l == 0) redB[wv] = z;
        __syncthreads();
        if (tid == 0) out[b] = Mcur + __logf(redB[0] + redB[1]);
    }
}

extern "C" void kernel_launch(void* const* d_in, const int* in_sizes, int n_in,
                              void* d_out, int out_size, void* d_ws, size_t ws_size,
                              hipStream_t stream) {
    const float* emissions   = (const float*)d_in[0];
    const int*   token_sizes = (const int*)d_in[1];
    const int*   targets     = (const int*)d_in[2];
    const float* transitions = (const float*)d_in[3];  // (1,1,128,128)
    const float* head        = (const float*)d_in[4];  // (1,1,128)
    const float* last        = (const float*)d_in[5];  // (1,1,128)
    float* out = (float*)d_out;                        // (2,64,1) flat

    crf_kernel<<<2 * Bq, 128, 0, stream>>>(emissions, token_sizes, targets,
                                           transitions, head, last, out);
}

// Round 12
// 172.201 us; speedup vs baseline: 2.5895x; 2.5895x over previous
//
#include <hip/hip_runtime.h>
#include <math.h>

#define Bq 64
#define Tq 1024
#define Nq 128

typedef __attribute__((ext_vector_type(2))) _Float16 h2;

#if defined(__has_builtin)
#  if __has_builtin(__builtin_amdgcn_fdot2)
#    define HAVE_FDOT2 1
#  endif
#  if __has_builtin(__builtin_amdgcn_rcpf)
#    define HAVE_RCPF 1
#  endif
#endif

__device__ __forceinline__ float dot2acc(h2 a, h2 b, float c) {
#ifdef HAVE_FDOT2
    return __builtin_amdgcn_fdot2(a, b, c, false);
#else
    return c + (float)a.x * (float)b.x + (float)a.y * (float)b.y;
#endif
}

__device__ __forceinline__ float fastrcp(float x) {
#ifdef HAVE_RCPF
    return __builtin_amdgcn_rcpf(x);
#else
    return 1.0f / x;
#endif
}

union Q16 { int4 v; h2 p[4]; };

#define EXP_NEG7 9.118819655545162e-4f

// ---------------------------------------------------------------------------
// One recursion step (R10-proven body, direction-agnostic).
//   reads rb (LDS, 128 f16), ss = <E-frag, p>;  pn = ss * ee * rcp(pm)*e^-7
//   (clamped), written to wb. Ledger Mcur += log(pm)+7. Emission pipeline:
//   ee0..2 ready, raw3..4 in flight, this body issues the load for rawRow.
// ---------------------------------------------------------------------------
__device__ __forceinline__ void step_core(
    int rawRow, int n, const float* __restrict__ em_n,
    const _Float16* __restrict__ rb, _Float16* __restrict__ wb,
    const h2 (&e)[64],
    float& ee0, float& ee1, float& ee2, float& raw3, float& raw4,
    float& Mcur, float& pOut, float& ssOut)
{
    __syncthreads();                       // rb fully written

    const int4* p4 = (const int4*)rb;
    Q16 U[16];
    #pragma unroll
    for (int q = 0; q < 16; ++q) U[q].v = p4[q];     // broadcast reads
    asm volatile("" ::: "memory");         // keep wb store below the reads

    // sampled max of p[0..3] — identical in every lane (broadcast values)
    float pm = fmaxf(fmaxf((float)U[0].p[0].x, (float)U[0].p[0].y),
                     fmaxf((float)U[0].p[1].x, (float)U[0].p[1].y));
    pm = fmaxf(pm, 1e-6f);
    const float f = ee0 * (fastrcp(pm) * EXP_NEG7);

    // issue emission load (consumed 5 steps later); floats across barriers
    const float raw5 = em_n[(size_t)rawRow * Nq];

    float s[4] = {0.f, 0.f, 0.f, 0.f};
    #pragma unroll
    for (int j = 0; j < 64; ++j)                     // static after unroll
        s[j & 3] = dot2acc(U[j >> 2].p[j & 3], e[j], s[j & 3]);
    const float ss = (s[0] + s[1]) + (s[2] + s[3]);
    ssOut = ss;

    const float pn = fminf(ss * f, 60000.0f);
    wb[n] = (_Float16)pn;
    pOut = pn;

    // side chains (loop-carried only on themselves)
    Mcur += __logf(pm) + 7.0f;
    const float eeN = __expf(raw3);
    ee0 = ee1; ee1 = ee2; ee2 = eeN;
    raw3 = raw4; raw4 = raw5;
}

// ---------------------------------------------------------------------------
// Blocks 0..63:    forward half-chain  (t = 1 .. tm),   E-columns
// Blocks 64..127:  backward half-chain (t = tsz-1 .. tm+1), E-rows
// Blocks 128..191: gold-path score
// 128 threads; lane owns state n = tid. Workspace: w_tm, beta, Mf, Mb.
// ---------------------------------------------------------------------------
__global__ __launch_bounds__(128, 1)
void crf_kernel(const float* __restrict__ emissions,
                const int* __restrict__ token_sizes,
                const int* __restrict__ targets,
                const float* __restrict__ transitions,
                const float* __restrict__ head,
                const float* __restrict__ last,
                float* __restrict__ wsW,    // [64][128] forward w_tm
                float* __restrict__ wsU,    // [64][128] backward beta
                float* __restrict__ wsMf,   // [64]
                float* __restrict__ wsMb,   // [64]
                float* __restrict__ out) {
    const int tid = threadIdx.x;
    const int bid = blockIdx.x;

    if (bid >= 2 * Bq) {
        // ---------------- score path ----------------
        const int b = bid - 2 * Bq;
        const int tsz = token_sizes[b];
        const int* tg = targets + b * Tq;
        const float* em = emissions + (size_t)b * Tq * Nq;
        float sc = 0.f;
        for (int t = tid; t < tsz; t += 128) {
            int cur = tg[t];
            sc += em[(size_t)t * Nq + cur];
            if (t >= 1) sc += transitions[tg[t - 1] * Nq + cur];
        }
        #pragma unroll
        for (int off = 32; off >= 1; off >>= 1)
            sc += __shfl_xor(sc, off, 64);
        __shared__ float wsum[2];
        if ((tid & 63) == 0) wsum[tid >> 6] = sc;
        __syncthreads();
        if (tid == 0)
            out[Bq + b] = wsum[0] + wsum[1] + head[tg[0]] + last[tg[tsz - 1]];
        return;
    }

    const bool isFwd = (bid < Bq);
    const int b = isFwd ? bid : (bid - Bq);
    const int n = tid;
    const int wv = tid >> 6;
    const int l = tid & 63;
    const float* em_c = emissions + (size_t)b * Tq * Nq;
    const float* em_n = em_c + n;
    const int tsz = token_sizes[b];      // in [T/2, T]
    const int tm = tsz >> 1;             // split point

    __shared__ __align__(16) _Float16 pbuf[2][Nq];
    __shared__ float redA[2];

    // E fragments: forward = column n of E (exp(trans[m][n]));
    //              backward = row n of E (exp(trans[n][m])).
    h2 e[64];
    if (isFwd) {
        #pragma unroll
        for (int j = 0; j < 64; ++j) {
            h2 v;
            v.x = (_Float16)__expf(transitions[(2 * j)     * Nq + n]);
            v.y = (_Float16)__expf(transitions[(2 * j + 1) * Nq + n]);
            e[j] = v;
        }
    } else {
        #pragma unroll
        for (int j = 0; j < 64; ++j) {
            h2 v;
            v.x = (_Float16)__expf(transitions[n * Nq + 2 * j]);
            v.y = (_Float16)__expf(transitions[n * Nq + 2 * j + 1]);
            e[j] = v;
        }
    }
    #pragma unroll
    for (int j = 0; j < 64; ++j) asm volatile("" : "+v"(e[j]));

    // init vector (log domain) + uniform M0 via block reduce
    const float v0 = isFwd ? (head[n] + em_n[0])
                           : (last[n] + em_n[(size_t)(tsz - 1) * Nq]);
    float Mcur;
    {
        float w = v0;
        #pragma unroll
        for (int off = 32; off >= 1; off >>= 1)
            w = fmaxf(w, __shfl_xor(w, off, 64));
        if (l == 0) redA[wv] = w;
        __syncthreads();
        Mcur = fmaxf(redA[0], redA[1]);
    }
    pbuf[0][n] = (_Float16)__expf(v0 - Mcur);   // in (0,1]

    const int nsteps = isFwd ? tm : (tsz - 1 - tm);   // >= 255

    // emission pipeline. Forward: body k (k=1..nsteps) consumes ee row k,
    // issues raw row min(k+5, tsz-1). Backward: body k (k=1..nsteps)
    // consumes ee row tsz-1-k, issues raw row max(tsz-6-k, 0).
    float ee0, ee1, ee2, raw3, raw4;
    if (isFwd) {
        ee0 = __expf(em_n[1 * Nq]);
        ee1 = __expf(em_n[2 * Nq]);
        ee2 = __expf(em_n[3 * Nq]);
        raw3 = em_n[4 * Nq];
        raw4 = em_n[5 * Nq];
    } else {
        ee0 = __expf(em_n[(size_t)(tsz - 2) * Nq]);
        ee1 = __expf(em_n[(size_t)(tsz - 3) * Nq]);
        ee2 = __expf(em_n[(size_t)(tsz - 4) * Nq]);
        raw3 = em_n[(size_t)(tsz - 5) * Nq];
        raw4 = em_n[(size_t)(tsz - 6) * Nq];
    }

    float pOut = 0.f, ssOut = 0.f, Msave = Mcur;
    _Float16* b0 = &pbuf[0][0];
    _Float16* b1 = &pbuf[1][0];

    // raw row for body k
    #define RAW_ROW(k) (isFwd ? min((k) + 5, tsz - 1) : max(tsz - 6 - (k), 0))

    int k = 1;
    for (; k + 3 <= nsteps; k += 4) {
        Msave = Mcur;
        step_core(RAW_ROW(k),     n, em_n, b0, b1, e, ee0, ee1, ee2, raw3, raw4, Mcur, pOut, ssOut);
        Msave = Mcur;
        step_core(RAW_ROW(k + 1), n, em_n, b1, b0, e, ee0, ee1, ee2, raw3, raw4, Mcur, pOut, ssOut);
        Msave = Mcur;
        step_core(RAW_ROW(k + 2), n, em_n, b0, b1, e, ee0, ee1, ee2, raw3, raw4, Mcur, pOut, ssOut);
        Msave = Mcur;
        step_core(RAW_ROW(k + 3), n, em_n, b1, b0, e, ee0, ee1, ee2, raw3, raw4, Mcur, pOut, ssOut);
    }
    if (k <= nsteps) {
        Msave = Mcur;
        step_core(RAW_ROW(k), n, em_n, b0, b1, e, ee0, ee1, ee2, raw3, raw4, Mcur, pOut, ssOut);
        ++k;
        if (k <= nsteps) {
            Msave = Mcur;
            step_core(RAW_ROW(k), n, em_n, b1, b0, e, ee0, ee1, ee2, raw3, raw4, Mcur, pOut, ssOut);
            ++k;
            if (k <= nsteps) {
                Msave = Mcur;
                step_core(RAW_ROW(k), n, em_n, b0, b1, e, ee0, ee1, ee2, raw3, raw4, Mcur, pOut, ssOut);
            }
        }
    }
    #undef RAW_ROW

    if (isFwd) {
        // w_tm[n] = pOut * e^{Mcur}  (pOut pairs with post-update ledger)
        wsW[b * Nq + n] = pOut;
        if (tid == 0) wsMf[b] = Mcur;
    } else {
        // beta[n] = ssOut * e^{Msave} (ss pairs with pre-update ledger)
        wsU[b * Nq + n] = ssOut;
        if (tid == 0) wsMb[b] = Msave;
    }
}

// ---------------------------------------------------------------------------
// Combine: out[b] = log( sum_n w_tm[n] * beta[n] ) + Mf + Mb
// ---------------------------------------------------------------------------
__global__ __launch_bounds__(64)
void crf_combine_kernel(const float* __restrict__ wsW,
                        const float* __restrict__ wsU,
                        const float* __restrict__ wsMf,
                        const float* __restrict__ wsMb,
                        float* __restrict__ out) {
    const int b = blockIdx.x;
    const int l = threadIdx.x;
    const float* w = wsW + b * Nq;
    const float* u = wsU + b * Nq;
    float z = w[l] * u[l] + w[l + 64] * u[l + 64];
    #pragma unroll
    for (int off = 32; off >= 1; off >>= 1)
        z += __shfl_xor(z, off, 64);
    if (l == 0) out[b] = __logf(z) + wsMf[b] + wsMb[b];
}

extern "C" void kernel_launch(void* const* d_in, const int* in_sizes, int n_in,
                              void* d_out, int out_size, void* d_ws, size_t ws_size,
                              hipStream_t stream) {
    const float* emissions   = (const float*)d_in[0];
    const int*   token_sizes = (const int*)d_in[1];
    const int*   targets     = (const int*)d_in[2];
    const float* transitions = (const float*)d_in[3];  // (1,1,128,128)
    const float* head        = (const float*)d_in[4];  // (1,1,128)
    const float* last        = (const float*)d_in[5];  // (1,1,128)
    float* out = (float*)d_out;                        // (2,64,1) flat

    float* wsW  = (float*)d_ws;                  // 64*128 f32
    float* wsU  = wsW + Bq * Nq;                 // 64*128 f32
    float* wsMf = wsU + Bq * Nq;                 // 64
    float* wsMb = wsMf + Bq;                     // 64

    crf_kernel<<<3 * Bq, 128, 0, stream>>>(emissions, token_sizes, targets,
                                           transitions, head, last,
                                           wsW, wsU, wsMf, wsMb, out);
    crf_combine_kernel<<<Bq, 64, 0, stream>>>(wsW, wsU, wsMf, wsMb, out);
}